// Round 4
// baseline (163.509 us; speedup 1.0000x reference)
//
#include <hip/hip_runtime.h>
#include <hip/hip_bf16.h>
#include <math.h>

// Problem constants (from reference): B=2, S=2048, D_MODEL=1024, H=16, D_K=64
#define SS 2048

typedef __attribute__((ext_vector_type(8))) __bf16 bf16x8;
typedef __attribute__((ext_vector_type(4))) float f32x4;
typedef __attribute__((ext_vector_type(16))) float f32x16;
typedef __attribute__((ext_vector_type(4))) unsigned int u32x4;

__device__ __forceinline__ f32x4 mfma16(bf16x8 a, bf16x8 b, f32x4 c) {
  return __builtin_amdgcn_mfma_f32_16x16x32_bf16(a, b, c, 0, 0, 0);
}
__device__ __forceinline__ f32x16 mfma32(bf16x8 a, bf16x8 b, f32x16 c) {
  return __builtin_amdgcn_mfma_f32_32x32x16_bf16(a, b, c, 0, 0, 0);
}

__device__ __forceinline__ void gld_lds16(const void* g, void* l) {
  __builtin_amdgcn_global_load_lds(
      (__attribute__((address_space(1))) void*)(g),
      (__attribute__((address_space(3))) void*)(l), 16, 0, 0);
}

#if __has_builtin(__builtin_amdgcn_exp2f)
#define EXP2F(x) __builtin_amdgcn_exp2f(x)
#else
#define EXP2F(x) __expf(0.69314718056f * (x))
#endif

__device__ __forceinline__ unsigned int cvtpk_bf16(float lo, float hi) {
  unsigned int r;
  asm("v_cvt_pk_bf16_f32 %0, %1, %2" : "=v"(r) : "v"(lo), "v"(hi));
  return r;
}
__device__ __forceinline__ void swap32(unsigned int& x, unsigned int& y) {
  asm("v_permlane32_swap_b32 %0, %1" : "+v"(x), "+v"(y));
}

// ---------- f32 -> bf16 convert, 8 elems/thread ----------
__global__ void cvt8_kernel(const float* __restrict__ s, __bf16* __restrict__ d, int n) {
  int i = (blockIdx.x * blockDim.x + threadIdx.x) * 8;
  if (i >= n) return;
  float4 a = *reinterpret_cast<const float4*>(s + i);
  float4 b = *reinterpret_cast<const float4*>(s + i + 4);
  bf16x8 o;
  o[0] = (__bf16)a.x; o[1] = (__bf16)a.y; o[2] = (__bf16)a.z; o[3] = (__bf16)a.w;
  o[4] = (__bf16)b.x; o[5] = (__bf16)b.y; o[6] = (__bf16)b.z; o[7] = (__bf16)b.w;
  *reinterpret_cast<bf16x8*>(d + i) = o;
}

// ---------- cos/sin table: tab[s*32+j] = (cos,sin)(pos[s] * 10000^(-j/32)) ----------
__global__ void trig_kernel(const int* __restrict__ pos, float2* __restrict__ tab) {
  int i = blockIdx.x * blockDim.x + threadIdx.x;
  if (i >= SS * 32) return;
  int s = i >> 5, j = i & 31;
  float p = (float)pos[s];
  float inv = exp2f((float)j * -0.41524101186098283f);  // -(2/64)*log2(10000)
  float f = p * inv;
  float sn, cs;
  sincosf(f, &sn, &cs);
  tab[i] = make_float2(cs, sn);
}

// ---------- C[M][N] = A[M][K] * B[N][K]^T  (m97 structure) ----------
// ROPE: apply rotary embedding in the epilogue for output cols < 2048
// (block-uniform since n0 is a multiple of 128). Pair (2j,2j+1) = adjacent
// lanes in the C/D layout -> one shfl_xor(1) exchange.
template <typename OutT, bool ROPE>
__global__ __launch_bounds__(256) void gemm_bt_kernel(
    const __bf16* __restrict__ A, const __bf16* __restrict__ Bw,
    OutT* __restrict__ C, int M, int N, int K, const float2* __restrict__ tab) {
  __shared__ __align__(16) __bf16 lA[128 * 32];
  __shared__ __align__(16) __bf16 lB[128 * 32];
  const int tid = threadIdx.x;
  const int lane = tid & 63;
  const int wave = tid >> 6;
  const int wr = wave >> 1, wc = wave & 1;
  const int m0 = blockIdx.y * 128, n0 = blockIdx.x * 128;

  const f32x4 fzero = {0.f, 0.f, 0.f, 0.f};
  f32x4 acc[4][4];
#pragma unroll
  for (int i = 0; i < 4; ++i)
#pragma unroll
    for (int j = 0; j < 4; ++j) acc[i][j] = fzero;

  const int srow = tid >> 2, scol = (tid & 3) * 8;
  const __bf16* gA = A + (size_t)(m0 + srow) * K + scol;
  const __bf16* gB = Bw + (size_t)(n0 + srow) * K + scol;
  __bf16* sA = lA + tid * 8;
  __bf16* sB = lB + tid * 8;
  const size_t half = (size_t)64 * K;

  const int lrow = lane & 15, lk8 = (lane >> 4) * 8;

  for (int kt = 0; kt < K; kt += 32) {
    gld_lds16(gA + kt, sA);
    gld_lds16(gA + kt + half, sA + 64 * 32);
    gld_lds16(gB + kt, sB);
    gld_lds16(gB + kt + half, sB + 64 * 32);
    __syncthreads();
    bf16x8 af[4], bfr[4];
#pragma unroll
    for (int i = 0; i < 4; ++i)
      af[i] = *reinterpret_cast<const bf16x8*>(lA + (wr * 64 + i * 16 + lrow) * 32 + lk8);
#pragma unroll
    for (int j = 0; j < 4; ++j)
      bfr[j] = *reinterpret_cast<const bf16x8*>(lB + (wc * 64 + j * 16 + lrow) * 32 + lk8);
#pragma unroll
    for (int i = 0; i < 4; ++i)
#pragma unroll
      for (int j = 0; j < 4; ++j) acc[i][j] = mfma16(af[i], bfr[j], acc[i][j]);
    __syncthreads();
  }

  // C/D layout: col = lane&15, row = (lane>>4)*4 + reg
  const int crow = (lane >> 4) * 4, ccol = lane & 15;
  if (ROPE && n0 < 2048) {
    const int par = ccol & 1;
#pragma unroll
    for (int i = 0; i < 4; ++i) {
#pragma unroll
      for (int t = 0; t < 4; ++t) {
        const int r = m0 + wr * 64 + i * 16 + crow + t;
        const int s = r & (SS - 1);
#pragma unroll
        for (int j = 0; j < 4; ++j) {
          const int jj = ((j * 16 + ccol) >> 1) & 31;
          float2 cs = tab[(s << 5) | jj];
          float v = acc[i][j][t];
          float o = __shfl_xor(v, 1);
          // even lane: y = v*cos - o*sin ; odd lane: y = o*sin + v*cos
          float y = par ? fmaf(o, cs.y, v * cs.x) : fmaf(v, cs.x, -o * cs.y);
          const int c = n0 + wc * 64 + j * 16 + ccol;
          C[(size_t)r * N + c] = (OutT)y;
        }
      }
    }
  } else {
#pragma unroll
    for (int i = 0; i < 4; ++i) {
#pragma unroll
      for (int j = 0; j < 4; ++j) {
        int r = m0 + wr * 64 + i * 16 + crow;
        int c = n0 + wc * 64 + j * 16 + ccol;
#pragma unroll
        for (int t = 0; t < 4; ++t) C[(size_t)(r + t) * N + c] = (OutT)acc[i][j][t];
      }
    }
  }
}

// ---------- V transpose: Vt[(b*16+h)*64 + d][s] = V[b,s,h,d] ----------
__global__ __launch_bounds__(256) void vtrans_kernel(const __bf16* __restrict__ qkv,
                                                     __bf16* __restrict__ Vt) {
  __shared__ __bf16 t[64][65];
  const int st = blockIdx.x, h = blockIdx.y, b = blockIdx.z;
  const int tid = threadIdx.x;
  const int sl = tid >> 2, c0 = (tid & 3) * 16;
  const __bf16* src = qkv + (size_t)(b * SS + st * 64 + sl) * 3072 + 2048 + h * 64 + c0;
  bf16x8 a0 = *reinterpret_cast<const bf16x8*>(src);
  bf16x8 a1 = *reinterpret_cast<const bf16x8*>(src + 8);
#pragma unroll
  for (int i = 0; i < 8; ++i) { t[c0 + i][sl] = a0[i]; t[c0 + 8 + i][sl] = a1[i]; }
  __syncthreads();
  __bf16* dst = Vt + (size_t)((b * 16 + h) * 64 + sl) * SS + st * 64 + c0;
  bf16x8 o0, o1;
#pragma unroll
  for (int i = 0; i < 8; ++i) { o0[i] = t[sl][c0 + i]; o1[i] = t[sl][c0 + 8 + i]; }
  *reinterpret_cast<bf16x8*>(dst) = o0;
  *reinterpret_cast<bf16x8*>(dst + 8) = o1;
}

// ---------- causal flash attention, 32x32 swapped-operand structure ----------
// Uniform paired blocks: block i processes q-tiles (15-i) then (i) -> every
// block does exactly 34 KV-tile rounds (no causal tail). 4 waves/block,
// 32 q-rows/wave, KV tile 64, dbuf LDS K/V via global_load_lds with
// source-side XOR swizzle. In-register softmax with defer-max (T13).
#define CEXP 0.18033688011112042f   // log2(e)/8
#define DMAX_THR 11.541560327111708f  // 8 * log2(e)

__global__ __launch_bounds__(256, 2) void attn_kernel(const __bf16* __restrict__ qkv,
                                                      const __bf16* __restrict__ Vt,
                                                      __bf16* __restrict__ AO) {
  const int h = blockIdx.y, b = blockIdx.z;
  const int tid = threadIdx.x;
  const int wave = tid >> 6, lane = tid & 63;
  const int q32 = lane & 31, hi = lane >> 5;

  __shared__ __align__(16) __bf16 lK[2][64 * 64];
  __shared__ __align__(16) __bf16 lV[2][64 * 64];
  __shared__ __align__(16) __bf16 lO[4][32 * 72];

  const __bf16* kbase = qkv + (size_t)(b * SS) * 3072 + 1024 + h * 64;
  const __bf16* vbase = Vt + (size_t)((b * 16 + h) * 64) * SS;

  // staging: LDS row r = tid>>3, chunk c = tid&7; source chunk pre-XOR'd
  const int srow = tid >> 3, scg = tid & 7;
  const int ssc = 8 * (scg ^ (srow & 7));
  const __bf16* kG0 = kbase + (size_t)srow * 3072 + ssc;
  const __bf16* vG0 = vbase + (size_t)srow * SS + ssc;

  for (int ph = 0; ph < 2; ++ph) {
    const int qt = ph ? (int)blockIdx.x : 15 - (int)blockIdx.x;
    const int qw0 = qt * 128 + wave * 32;
    const int q = qw0 + q32;

    // Q fragments (B-operand of QK^T): lane holds Q[q][slot*16 + hi*8 + 0..7]
    bf16x8 qb[4];
    {
      const __bf16* qr = qkv + (size_t)(b * SS + q) * 3072 + h * 64;
#pragma unroll
      for (int slot = 0; slot < 4; ++slot)
        qb[slot] = *reinterpret_cast<const bf16x8*>(qr + slot * 16 + hi * 8);
    }

    f32x16 o0 = {0,0,0,0,0,0,0,0,0,0,0,0,0,0,0,0};
    f32x16 o1 = {0,0,0,0,0,0,0,0,0,0,0,0,0,0,0,0};
    float mB = -INFINITY, lsum = 0.f;

    const int nkt = 2 * (qt + 1);

    // prologue: stage tile 0 into buf 0
    gld_lds16(kG0, lK[0] + tid * 8);
    gld_lds16(kG0 + (size_t)32 * 3072, lK[0] + tid * 8 + 2048);
    gld_lds16(vG0, lV[0] + tid * 8);
    gld_lds16(vG0 + (size_t)32 * SS, lV[0] + tid * 8 + 2048);
    __syncthreads();

    for (int kt = 0; kt < nkt; ++kt) {
      const int buf = kt & 1;
      const int kvb = kt * 64;
      if (kt + 1 < nkt) {  // prefetch next tile into other buffer
        const __bf16* kG = kG0 + (size_t)(kvb + 64) * 3072;
        const __bf16* vG = vG0 + (kvb + 64);
        gld_lds16(kG, lK[buf ^ 1] + tid * 8);
        gld_lds16(kG + (size_t)32 * 3072, lK[buf ^ 1] + tid * 8 + 2048);
        gld_lds16(vG, lV[buf ^ 1] + tid * 8);
        gld_lds16(vG + (size_t)32 * SS, lV[buf ^ 1] + tid * 8 + 2048);
      }

      if (kvb <= qw0 + 31) {  // wave-active (wave-uniform)
        // ---- QK^T: S^T[64 kv][32 q] = K-tile * Q^T, contract d=64 ----
        f32x16 s0 = {0,0,0,0,0,0,0,0,0,0,0,0,0,0,0,0};
        f32x16 s1 = {0,0,0,0,0,0,0,0,0,0,0,0,0,0,0,0};
        __builtin_amdgcn_s_setprio(1);
#pragma unroll
        for (int slot = 0; slot < 4; ++slot) {
          const int swz = 8 * ((slot * 2 + hi) ^ (q32 & 7));
          bf16x8 k0 = *reinterpret_cast<const bf16x8*>(lK[buf] + q32 * 64 + swz);
          bf16x8 k1 = *reinterpret_cast<const bf16x8*>(lK[buf] + (32 + q32) * 64 + swz);
          s0 = mfma32(k0, qb[slot], s0);
          s1 = mfma32(k1, qb[slot], s1);
        }
        __builtin_amdgcn_s_setprio(0);

        // ---- causal mask (only diagonal-region tiles) ----
        if (kvb + 63 > qw0) {
#pragma unroll
          for (int r = 0; r < 16; ++r) {
            const int rowc = (r & 3) + 8 * (r >> 2) + 4 * hi;
            if (kvb + rowc > q) s0[r] = -INFINITY;
            if (kvb + 32 + rowc > q) s1[r] = -INFINITY;
          }
        }

        // ---- online softmax, lane-local row, defer-max (T13) ----
        float pm = s0[0];
#pragma unroll
        for (int r = 1; r < 16; ++r) pm = fmaxf(pm, s0[r]);
#pragma unroll
        for (int r = 0; r < 16; ++r) pm = fmaxf(pm, s1[r]);
        pm = fmaxf(pm, __shfl_xor(pm, 32));
        const float pmB = pm * CEXP;
        if (!__all(pmB <= mB + DMAX_THR)) {
          const float mnB = fmaxf(mB, pmB);
          const float alpha = EXP2F(mB - mnB);
          mB = mnB;
          lsum *= alpha;
#pragma unroll
          for (int r = 0; r < 16; ++r) { o0[r] *= alpha; o1[r] *= alpha; }
        }
        float rs = 0.f;
#pragma unroll
        for (int r = 0; r < 16; ++r) {
          s0[r] = EXP2F(fmaf(s0[r], CEXP, -mB));
          rs += s0[r];
        }
#pragma unroll
        for (int r = 0; r < 16; ++r) {
          s1[r] = EXP2F(fmaf(s1[r], CEXP, -mB));
          rs += s1[r];
        }
        rs += __shfl_xor(rs, 32);
        lsum += rs;

        // ---- P -> bf16 PV fragments (cvt_pk + permlane32_swap) ----
        bf16x8 pb[4];
        {
          unsigned int A = cvtpk_bf16(s0[0], s0[1]), B2 = cvtpk_bf16(s0[2], s0[3]);
          unsigned int C2 = cvtpk_bf16(s0[4], s0[5]), D2 = cvtpk_bf16(s0[6], s0[7]);
          swap32(A, C2); swap32(B2, D2);
          u32x4 t0 = {A, B2, C2, D2};
          pb[0] = __builtin_bit_cast(bf16x8, t0);
          unsigned int E = cvtpk_bf16(s0[8], s0[9]), F = cvtpk_bf16(s0[10], s0[11]);
          unsigned int G = cvtpk_bf16(s0[12], s0[13]), H = cvtpk_bf16(s0[14], s0[15]);
          swap32(E, G); swap32(F, H);
          u32x4 t1 = {E, F, G, H};
          pb[1] = __builtin_bit_cast(bf16x8, t1);
          unsigned int A3 = cvtpk_bf16(s1[0], s1[1]), B3 = cvtpk_bf16(s1[2], s1[3]);
          unsigned int C3 = cvtpk_bf16(s1[4], s1[5]), D3 = cvtpk_bf16(s1[6], s1[7]);
          swap32(A3, C3); swap32(B3, D3);
          u32x4 t2 = {A3, B3, C3, D3};
          pb[2] = __builtin_bit_cast(bf16x8, t2);
          unsigned int E3 = cvtpk_bf16(s1[8], s1[9]), F3 = cvtpk_bf16(s1[10], s1[11]);
          unsigned int G3 = cvtpk_bf16(s1[12], s1[13]), H3 = cvtpk_bf16(s1[14], s1[15]);
          swap32(E3, G3); swap32(F3, H3);
          u32x4 t3 = {E3, F3, G3, H3};
          pb[3] = __builtin_bit_cast(bf16x8, t3);
        }

        // ---- PV: O^T[64 d][32 q] += V^T-slot * P^T-slot ----
        __builtin_amdgcn_s_setprio(1);
#pragma unroll
        for (int slot = 0; slot < 4; ++slot) {
          const int swz = 8 * ((slot * 2 + hi) ^ (q32 & 7));
          bf16x8 v0 = *reinterpret_cast<const bf16x8*>(lV[buf] + q32 * 64 + swz);
          bf16x8 v1 = *reinterpret_cast<const bf16x8*>(lV[buf] + (32 + q32) * 64 + swz);
          o0 = mfma32(v0, pb[slot], o0);
          o1 = mfma32(v1, pb[slot], o1);
        }
        __builtin_amdgcn_s_setprio(0);
      }
      __syncthreads();  // staged loads drained + all waves done with buf
    }

    // ---- epilogue: O^T/lsum -> per-wave LDS transpose -> coalesced stores ----
    const float inv = 1.0f / lsum;
    __bf16* ol = lO[wave];
#pragma unroll
    for (int r = 0; r < 16; ++r) {
      const int d = (r & 3) + 8 * (r >> 2) + 4 * hi;
      ol[q32 * 72 + d] = (__bf16)(o0[r] * inv);
      ol[q32 * 72 + 32 + d] = (__bf16)(o1[r] * inv);
    }
    // per-wave buffer: no barrier needed (compiler inserts lgkmcnt waits)
#pragma unroll
    for (int pass = 0; pass < 4; ++pass) {
      const int idx = pass * 64 + lane;
      const int row = idx >> 3, colc = idx & 7;
      bf16x8 v = *reinterpret_cast<const bf16x8*>(ol + row * 72 + colc * 8);
      *reinterpret_cast<bf16x8*>(
          AO + (size_t)(b * SS + qt * 128 + wave * 32 + row) * 1024 + h * 64 + colc * 8) = v;
    }
  }
}

extern "C" void kernel_launch(void* const* d_in, const int* in_sizes, int n_in,
                              void* d_out, int out_size, void* d_ws, size_t ws_size,
                              hipStream_t stream) {
  const float* x  = (const float*)d_in[0];
  const int* pos  = (const int*)d_in[1];
  const float* Wq = (const float*)d_in[2];
  const float* Wk = (const float*)d_in[3];
  const float* Wv = (const float*)d_in[4];
  const float* Wo = (const float*)d_in[5];

  __bf16* xb  = (__bf16*)d_ws;                        // [4096][1024]
  __bf16* Wb  = xb + (size_t)4096 * 1024;             // [4096][1024] = Wq;Wk;Wv;Wo stacked
  __bf16* qkv = Wb + (size_t)4096 * 1024;             // [4096][3072] (q|k|v cols)
  __bf16* Vt  = qkv + (size_t)4096 * 3072;            // [2*16*64][2048]
  __bf16* ao  = Vt + (size_t)2048 * 2048;             // [4096][1024]
  float2* tab = (float2*)(ao + (size_t)4096 * 1024);  // [2048*32]

  cvt8_kernel<<<2048, 256, 0, stream>>>(x, xb, 4096 * 1024);
  cvt8_kernel<<<512, 256, 0, stream>>>(Wq, Wb, 1024 * 1024);
  cvt8_kernel<<<512, 256, 0, stream>>>(Wk, Wb + (size_t)1024 * 1024, 1024 * 1024);
  cvt8_kernel<<<512, 256, 0, stream>>>(Wv, Wb + (size_t)2 * 1024 * 1024, 1024 * 1024);
  cvt8_kernel<<<512, 256, 0, stream>>>(Wo, Wb + (size_t)3 * 1024 * 1024, 1024 * 1024);
  trig_kernel<<<256, 256, 0, stream>>>(pos, tab);

  // fused QKV projection + RoPE epilogue
  gemm_bt_kernel<__bf16, true><<<dim3(24, 32), 256, 0, stream>>>(
      xb, Wb, qkv, 4096, 3072, 1024, tab);
  vtrans_kernel<<<dim3(32, 16, 2), 256, 0, stream>>>(qkv, Vt);
  attn_kernel<<<dim3(8, 16, 2), 256, 0, stream>>>(qkv, Vt, ao);
  gemm_bt_kernel<float, false><<<dim3(8, 32), 256, 0, stream>>>(
      ao, Wb + (size_t)3 * 1024 * 1024, (float*)d_out, 4096, 1024, 1024, nullptr);
}

// Round 5
// 131.436 us; speedup vs baseline: 1.2440x; 1.2440x over previous
//
#include <hip/hip_runtime.h>
#include <hip/hip_bf16.h>
#include <math.h>

// Problem constants (from reference): B=2, S=2048, D_MODEL=1024, H=16, D_K=64
#define SS 2048

typedef __attribute__((ext_vector_type(8))) __bf16 bf16x8;
typedef __attribute__((ext_vector_type(4))) float f32x4;
typedef __attribute__((ext_vector_type(16))) float f32x16;
typedef __attribute__((ext_vector_type(4))) unsigned int u32x4;
typedef __attribute__((ext_vector_type(4))) unsigned short u16x4;

__device__ __forceinline__ f32x4 mfma16(bf16x8 a, bf16x8 b, f32x4 c) {
  return __builtin_amdgcn_mfma_f32_16x16x32_bf16(a, b, c, 0, 0, 0);
}
__device__ __forceinline__ f32x16 mfma32(bf16x8 a, bf16x8 b, f32x16 c) {
  return __builtin_amdgcn_mfma_f32_32x32x16_bf16(a, b, c, 0, 0, 0);
}

__device__ __forceinline__ void gld_lds16(const void* g, void* l) {
  __builtin_amdgcn_global_load_lds(
      (__attribute__((address_space(1))) void*)(g),
      (__attribute__((address_space(3))) void*)(l), 16, 0, 0);
}

#if __has_builtin(__builtin_amdgcn_exp2f)
#define EXP2F(x) __builtin_amdgcn_exp2f(x)
#else
#define EXP2F(x) __expf(0.69314718056f * (x))
#endif

__device__ __forceinline__ unsigned int cvtpk_bf16(float lo, float hi) {
  unsigned int r;
  asm("v_cvt_pk_bf16_f32 %0, %1, %2" : "=v"(r) : "v"(lo), "v"(hi));
  return r;
}
__device__ __forceinline__ void swap32(unsigned int& x, unsigned int& y) {
  asm("v_permlane32_swap_b32 %0, %1" : "+v"(x), "+v"(y));
}
__device__ __forceinline__ unsigned short bfu(float v) {
  __bf16 h = (__bf16)v;
  return __builtin_bit_cast(unsigned short, h);
}

// ---------- fused: f32->bf16 converts (x, Wq..Wo) + trig table ----------
__global__ void prep_kernel(const float* __restrict__ x, const float* __restrict__ Wq,
                            const float* __restrict__ Wk, const float* __restrict__ Wv,
                            const float* __restrict__ Wo, const int* __restrict__ pos,
                            __bf16* __restrict__ xb, __bf16* __restrict__ Wb,
                            float2* __restrict__ tab) {
  const int bid = blockIdx.x, tid = threadIdx.x;
  if (bid >= 4096) {  // trig table: 256 blocks x 256 threads = 65536 = 2048*32
    int i = (bid - 4096) * 256 + tid;
    int s = i >> 5, j = i & 31;
    float p = (float)pos[s];
    float inv = exp2f((float)j * -0.41524101186098283f);  // -(2/64)*log2(10000)
    float f = p * inv;
    float sn, cs;
    sincosf(f, &sn, &cs);
    tab[i] = make_float2(cs, sn);
    return;
  }
  const float* s;
  __bf16* d;
  size_t base;
  if (bid < 2048) { s = x; d = xb; base = bid; }
  else {
    int seg = (bid - 2048) >> 9;  // 0..3, block-uniform
    s = (seg == 0) ? Wq : (seg == 1) ? Wk : (seg == 2) ? Wv : Wo;
    d = Wb + (size_t)seg * 1024 * 1024;
    base = (bid - 2048) & 511;
  }
  size_t i = (base * 256 + tid) * 8;
  float4 a = *reinterpret_cast<const float4*>(s + i);
  float4 b = *reinterpret_cast<const float4*>(s + i + 4);
  bf16x8 o;
  o[0] = (__bf16)a.x; o[1] = (__bf16)a.y; o[2] = (__bf16)a.z; o[3] = (__bf16)a.w;
  o[4] = (__bf16)b.x; o[5] = (__bf16)b.y; o[6] = (__bf16)b.z; o[7] = (__bf16)b.w;
  *reinterpret_cast<bf16x8*>(d + i) = o;
}

// ---------- C[M][N] = A[M][K] * B[N][K]^T, dbuf LDS + early prefetch ----------
// 1D grid with bijective XCD swizzle (nwg % 8 == 0), M-fastest within XCD.
// MODE 0: plain store (OutT). MODE 1 (QKV): cols<2048 -> RoPE into qkv;
// cols>=2048 -> V written TRANSPOSED into Vt[(b*16+h)*64+d][s].
template <typename OutT, int MODE>
__global__ __launch_bounds__(256) void gemm_bt_kernel(
    const __bf16* __restrict__ A, const __bf16* __restrict__ Bw,
    OutT* __restrict__ C, __bf16* __restrict__ Vt,
    int MT, int N, int K, const float2* __restrict__ tab) {
  __shared__ __align__(16) __bf16 lA[2][128 * 32];
  __shared__ __align__(16) __bf16 lB[2][128 * 32];
  const int tid = threadIdx.x;
  const int lane = tid & 63;
  const int wave = tid >> 6;
  const int wr = wave >> 1, wc = wave & 1;

  const int cpx = (int)gridDim.x >> 3;
  const int flat = blockIdx.x;
  const int wg = (flat & 7) * cpx + (flat >> 3);
  const int m0 = (wg % MT) * 128, n0 = (wg / MT) * 128;

  const f32x4 fzero = {0.f, 0.f, 0.f, 0.f};
  f32x4 acc[4][4];
#pragma unroll
  for (int i = 0; i < 4; ++i)
#pragma unroll
    for (int j = 0; j < 4; ++j) acc[i][j] = fzero;

  const int srow = tid >> 2, scol = (tid & 3) * 8;
  const __bf16* gA = A + (size_t)(m0 + srow) * K + scol;
  const __bf16* gB = Bw + (size_t)(n0 + srow) * K + scol;
  const size_t half = (size_t)64 * K;
  const int lrow = lane & 15, lk8 = (lane >> 4) * 8;

  // prologue: stage k-tile 0 into buf 0
  gld_lds16(gA, &lA[0][tid * 8]);
  gld_lds16(gA + half, &lA[0][tid * 8 + 2048]);
  gld_lds16(gB, &lB[0][tid * 8]);
  gld_lds16(gB + half, &lB[0][tid * 8 + 2048]);
  __syncthreads();

  const int nk = K >> 5;
  for (int t = 0; t < nk; ++t) {
    const int buf = t & 1;
    if (t + 1 < nk) {  // early prefetch: flies during ds_read + MFMA below
      const int kt = (t + 1) * 32;
      gld_lds16(gA + kt, &lA[buf ^ 1][tid * 8]);
      gld_lds16(gA + kt + half, &lA[buf ^ 1][tid * 8 + 2048]);
      gld_lds16(gB + kt, &lB[buf ^ 1][tid * 8]);
      gld_lds16(gB + kt + half, &lB[buf ^ 1][tid * 8 + 2048]);
    }
    bf16x8 af[4], bfr[4];
#pragma unroll
    for (int i = 0; i < 4; ++i)
      af[i] = *reinterpret_cast<const bf16x8*>(&lA[buf][(wr * 64 + i * 16 + lrow) * 32 + lk8]);
#pragma unroll
    for (int j = 0; j < 4; ++j)
      bfr[j] = *reinterpret_cast<const bf16x8*>(&lB[buf][(wc * 64 + j * 16 + lrow) * 32 + lk8]);
    __builtin_amdgcn_s_setprio(1);
#pragma unroll
    for (int i = 0; i < 4; ++i)
#pragma unroll
      for (int j = 0; j < 4; ++j) acc[i][j] = mfma16(af[i], bfr[j], acc[i][j]);
    __builtin_amdgcn_s_setprio(0);
    __syncthreads();  // drains prefetch (vmcnt 0) + all waves done reading buf
  }

  // C/D layout: col = lane&15, row = (lane>>4)*4 + reg
  const int crow = (lane >> 4) * 4, ccol = lane & 15;
  if (MODE == 1 && n0 < 2048) {  // q,k columns: RoPE epilogue
    const int par = ccol & 1;
#pragma unroll
    for (int i = 0; i < 4; ++i) {
#pragma unroll
      for (int t = 0; t < 4; ++t) {
        const int r = m0 + wr * 64 + i * 16 + crow + t;
        const int s = r & (SS - 1);
#pragma unroll
        for (int j = 0; j < 4; ++j) {
          const int jj = ((j * 16 + ccol) >> 1) & 31;
          float2 cs = tab[(s << 5) | jj];
          float v = acc[i][j][t];
          float o = __shfl_xor(v, 1);
          float y = par ? fmaf(o, cs.y, v * cs.x) : fmaf(v, cs.x, -o * cs.y);
          const int c = n0 + wc * 64 + j * 16 + ccol;
          C[(size_t)r * N + c] = (OutT)y;
        }
      }
    }
  } else if (MODE == 1) {  // V columns: write transposed into Vt
#pragma unroll
    for (int i = 0; i < 4; ++i) {
      const int r0 = m0 + wr * 64 + i * 16 + crow;  // +t stays in same batch
      const int bb = r0 >> 11, s0 = r0 & (SS - 1);
#pragma unroll
      for (int j = 0; j < 4; ++j) {
        const int c = n0 - 2048 + wc * 64 + j * 16 + ccol;
        const int hh = c >> 6, dd = c & 63;
        u16x4 pk;
#pragma unroll
        for (int t = 0; t < 4; ++t) pk[t] = bfu(acc[i][j][t]);
        *reinterpret_cast<u16x4*>(Vt + ((size_t)(bb * 16 + hh) * 64 + dd) * SS + s0) = pk;
      }
    }
  } else {
#pragma unroll
    for (int i = 0; i < 4; ++i) {
#pragma unroll
      for (int j = 0; j < 4; ++j) {
        int r = m0 + wr * 64 + i * 16 + crow;
        int c = n0 + wc * 64 + j * 16 + ccol;
#pragma unroll
        for (int t = 0; t < 4; ++t) C[(size_t)(r + t) * N + c] = (OutT)acc[i][j][t];
      }
    }
  }
}

// ---------- causal flash attention, 32x32 swapped-operand structure ----------
// 2 waves/block (128 thr), 64 q-rows/block (32/wave), KV tile 64, dbuf LDS
// via global_load_lds with source-side XOR swizzle. Grid 1024 = 4 blocks/CU
// (8 waves/CU); bid->qt map makes each CU-group {g=0..3, same c} sum to 66
// rounds: qt in {low, 31-low, 15-low, 16+low}. In-register softmax,
// defer-max (T13), cvt_pk+permlane P conversion (T12), setprio (T5).
#define CEXP 0.18033688011112042f    // log2(e)/8
#define DMAX_THR 11.541560327111708f  // 8 * log2(e)

__global__ __launch_bounds__(128) void attn_kernel(const __bf16* __restrict__ qkv,
                                                   const __bf16* __restrict__ Vt,
                                                   __bf16* __restrict__ AO) {
  const int bid = blockIdx.x;
  const int g = bid >> 8, c = bid & 255;
  const int b = c >> 7, h = (c >> 3) & 15, low = c & 7;
  const int qt = (g == 0) ? low : (g == 1) ? 31 - low : (g == 2) ? 15 - low : 16 + low;

  const int tid = threadIdx.x;
  const int wave = tid >> 6, lane = tid & 63;
  const int q32 = lane & 31, hi = lane >> 5;
  const int qw0 = qt * 64 + wave * 32;
  const int q = qw0 + q32;

  __shared__ __align__(16) __bf16 smem[16384];  // 32 KB: lK[2]|lV[2]; lO aliases
  __bf16* lK0 = smem;
  __bf16* lV0 = smem + 8192;

  // Q fragments (B-operand of QK^T): lane holds Q[q][slot*16 + hi*8 + 0..7]
  bf16x8 qb[4];
  {
    const __bf16* qr = qkv + (size_t)(b * SS + q) * 3072 + h * 64;
#pragma unroll
    for (int slot = 0; slot < 4; ++slot)
      qb[slot] = *reinterpret_cast<const bf16x8*>(qr + slot * 16 + hi * 8);
  }

  const __bf16* kbase = qkv + (size_t)(b * SS) * 3072 + 1024 + h * 64;
  const __bf16* vbase = Vt + (size_t)((b * 16 + h) * 64) * SS;

  // staging: each thread stages rows srow+16u, chunk scg; source col pre-XOR'd
  const int srow = tid >> 3, scg = tid & 7;
  const int ssc = 8 * (scg ^ (srow & 7));
  const __bf16* kG0 = kbase + (size_t)srow * 3072 + ssc;
  const __bf16* vG0 = vbase + (size_t)srow * SS + ssc;

#define STAGE(buf_, kt_)                                                      \
  do {                                                                        \
    const __bf16* kG = kG0 + (size_t)(kt_)*64 * 3072;                         \
    const __bf16* vG = vG0 + (size_t)(kt_)*64;                                \
    _Pragma("unroll") for (int u = 0; u < 4; ++u) {                           \
      gld_lds16(kG + (size_t)u * 16 * 3072, lK0 + (buf_)*4096 + tid * 8 + u * 1024); \
      gld_lds16(vG + (size_t)u * 16 * SS, lV0 + (buf_)*4096 + tid * 8 + u * 1024);   \
    }                                                                         \
  } while (0)

  f32x16 o0 = {0,0,0,0,0,0,0,0,0,0,0,0,0,0,0,0};
  f32x16 o1 = {0,0,0,0,0,0,0,0,0,0,0,0,0,0,0,0};
  float mB = -INFINITY, lsum = 0.f;

  const int nkt = qt + 1;
  STAGE(0, 0);
  __syncthreads();

  for (int kt = 0; kt < nkt; ++kt) {
    const int buf = kt & 1;
    const int kvb = kt * 64;
    if (kt + 1 < nkt) STAGE(buf ^ 1, kt + 1);  // early prefetch

    const __bf16* lk = lK0 + buf * 4096;
    const __bf16* lv = lV0 + buf * 4096;

    // ---- QK^T: S^T[64 kv][32 q] = K-tile * Q^T, contract d=64 ----
    f32x16 s0 = {0,0,0,0,0,0,0,0,0,0,0,0,0,0,0,0};
    f32x16 s1 = {0,0,0,0,0,0,0,0,0,0,0,0,0,0,0,0};
    __builtin_amdgcn_s_setprio(1);
#pragma unroll
    for (int slot = 0; slot < 4; ++slot) {
      const int swz = 8 * ((slot * 2 + hi) ^ (q32 & 7));
      bf16x8 k0 = *reinterpret_cast<const bf16x8*>(lk + q32 * 64 + swz);
      bf16x8 k1 = *reinterpret_cast<const bf16x8*>(lk + (32 + q32) * 64 + swz);
      s0 = mfma32(k0, qb[slot], s0);
      s1 = mfma32(k1, qb[slot], s1);
    }
    __builtin_amdgcn_s_setprio(0);

    // ---- causal mask: only the diagonal tile needs it ----
    if (kt == qt) {
#pragma unroll
      for (int r = 0; r < 16; ++r) {
        const int rowc = (r & 3) + 8 * (r >> 2) + 4 * hi;
        if (kvb + rowc > q) s0[r] = -INFINITY;
        if (kvb + 32 + rowc > q) s1[r] = -INFINITY;
      }
    }

    // ---- online softmax, lane-local row, defer-max ----
    float pm = s0[0];
#pragma unroll
    for (int r = 1; r < 16; ++r) pm = fmaxf(pm, s0[r]);
#pragma unroll
    for (int r = 0; r < 16; ++r) pm = fmaxf(pm, s1[r]);
    pm = fmaxf(pm, __shfl_xor(pm, 32));
    const float pmB = pm * CEXP;
    if (!__all(pmB <= mB + DMAX_THR)) {
      const float mnB = fmaxf(mB, pmB);
      const float alpha = EXP2F(mB - mnB);
      mB = mnB;
      lsum *= alpha;
#pragma unroll
      for (int r = 0; r < 16; ++r) { o0[r] *= alpha; o1[r] *= alpha; }
    }
    float rs = 0.f;
#pragma unroll
    for (int r = 0; r < 16; ++r) { s0[r] = EXP2F(fmaf(s0[r], CEXP, -mB)); rs += s0[r]; }
#pragma unroll
    for (int r = 0; r < 16; ++r) { s1[r] = EXP2F(fmaf(s1[r], CEXP, -mB)); rs += s1[r]; }
    rs += __shfl_xor(rs, 32);
    lsum += rs;

    // ---- P -> bf16 PV fragments (cvt_pk + permlane32_swap) ----
    bf16x8 pb[4];
    {
      unsigned int A = cvtpk_bf16(s0[0], s0[1]), B2 = cvtpk_bf16(s0[2], s0[3]);
      unsigned int C2 = cvtpk_bf16(s0[4], s0[5]), D2 = cvtpk_bf16(s0[6], s0[7]);
      swap32(A, C2); swap32(B2, D2);
      u32x4 t0 = {A, B2, C2, D2};
      pb[0] = __builtin_bit_cast(bf16x8, t0);
      unsigned int E = cvtpk_bf16(s0[8], s0[9]), F = cvtpk_bf16(s0[10], s0[11]);
      unsigned int G = cvtpk_bf16(s0[12], s0[13]), H = cvtpk_bf16(s0[14], s0[15]);
      swap32(E, G); swap32(F, H);
      u32x4 t1 = {E, F, G, H};
      pb[1] = __builtin_bit_cast(bf16x8, t1);
      unsigned int A3 = cvtpk_bf16(s1[0], s1[1]), B3 = cvtpk_bf16(s1[2], s1[3]);
      unsigned int C3 = cvtpk_bf16(s1[4], s1[5]), D3 = cvtpk_bf16(s1[6], s1[7]);
      swap32(A3, C3); swap32(B3, D3);
      u32x4 t2 = {A3, B3, C3, D3};
      pb[2] = __builtin_bit_cast(bf16x8, t2);
      unsigned int E3 = cvtpk_bf16(s1[8], s1[9]), F3 = cvtpk_bf16(s1[10], s1[11]);
      unsigned int G3 = cvtpk_bf16(s1[12], s1[13]), H3 = cvtpk_bf16(s1[14], s1[15]);
      swap32(E3, G3); swap32(F3, H3);
      u32x4 t3 = {E3, F3, G3, H3};
      pb[3] = __builtin_bit_cast(bf16x8, t3);
    }

    // ---- PV: O^T[64 d][32 q] += V^T-slot * P^T-slot ----
    __builtin_amdgcn_s_setprio(1);
#pragma unroll
    for (int slot = 0; slot < 4; ++slot) {
      const int swz = 8 * ((slot * 2 + hi) ^ (q32 & 7));
      bf16x8 v0 = *reinterpret_cast<const bf16x8*>(lv + q32 * 64 + swz);
      bf16x8 v1 = *reinterpret_cast<const bf16x8*>(lv + (32 + q32) * 64 + swz);
      o0 = mfma32(v0, pb[slot], o0);
      o1 = mfma32(v1, pb[slot], o1);
    }
    __builtin_amdgcn_s_setprio(0);

    __syncthreads();  // staged loads drained + all waves done with buf
  }

  // ---- epilogue: O^T/lsum -> per-wave LDS transpose -> coalesced stores ----
  const float inv = 1.0f / lsum;
  __bf16* ol = smem + wave * 2304;  // aliases lK (safe: after final barrier)
#pragma unroll
  for (int r = 0; r < 16; ++r) {
    const int d = (r & 3) + 8 * (r >> 2) + 4 * hi;
    ol[q32 * 72 + d] = (__bf16)(o0[r] * inv);
    ol[q32 * 72 + 32 + d] = (__bf16)(o1[r] * inv);
  }
  // per-wave buffer: in-wave lgkm ordering suffices, no barrier needed
#pragma unroll
  for (int pass = 0; pass < 4; ++pass) {
    const int idx = pass * 64 + lane;
    const int row = idx >> 3, colc = idx & 7;
    bf16x8 v = *reinterpret_cast<const bf16x8*>(ol + row * 72 + colc * 8);
    *reinterpret_cast<bf16x8*>(
        AO + (size_t)(b * SS + qt * 64 + wave * 32 + row) * 1024 + h * 64 + colc * 8) = v;
  }
#undef STAGE
}

extern "C" void kernel_launch(void* const* d_in, const int* in_sizes, int n_in,
                              void* d_out, int out_size, void* d_ws, size_t ws_size,
                              hipStream_t stream) {
  const float* x  = (const float*)d_in[0];
  const int* pos  = (const int*)d_in[1];
  const float* Wq = (const float*)d_in[2];
  const float* Wk = (const float*)d_in[3];
  const float* Wv = (const float*)d_in[4];
  const float* Wo = (const float*)d_in[5];

  __bf16* xb  = (__bf16*)d_ws;                        // [4096][1024]
  __bf16* Wb  = xb + (size_t)4096 * 1024;             // [4096][1024] = Wq;Wk;Wv;Wo stacked
  __bf16* qkv = Wb + (size_t)4096 * 1024;             // [4096][3072] (q|k cols live; v unused)
  __bf16* Vt  = qkv + (size_t)4096 * 3072;            // [2*16*64][2048]
  __bf16* ao  = Vt + (size_t)2048 * 2048;             // [4096][1024]
  float2* tab = (float2*)(ao + (size_t)4096 * 1024);  // [2048*32]

  prep_kernel<<<4352, 256, 0, stream>>>(x, Wq, Wk, Wv, Wo, pos, xb, Wb, tab);

  // fused QKV projection + RoPE + V-transpose epilogue
  gemm_bt_kernel<__bf16, 1><<<768, 256, 0, stream>>>(
      xb, Wb, qkv, Vt, 32, 3072, 1024, tab);
  attn_kernel<<<1024, 128, 0, stream>>>(qkv, Vt, ao);
  gemm_bt_kernel<float, 0><<<256, 256, 0, stream>>>(
      ao, Wb + (size_t)3 * 1024 * 1024, (float*)d_out, nullptr, 32, 1024, 1024, nullptr);
}

// Round 6
// 128.071 us; speedup vs baseline: 1.2767x; 1.0263x over previous
//
#include <hip/hip_runtime.h>
#include <hip/hip_bf16.h>
#include <math.h>

// Problem constants (from reference): B=2, S=2048, D_MODEL=1024, H=16, D_K=64
#define SS 2048

typedef __attribute__((ext_vector_type(8))) __bf16 bf16x8;
typedef __attribute__((ext_vector_type(4))) float f32x4;
typedef __attribute__((ext_vector_type(16))) float f32x16;
typedef __attribute__((ext_vector_type(4))) unsigned int u32x4;
typedef __attribute__((ext_vector_type(4))) unsigned short u16x4;

__device__ __forceinline__ f32x4 mfma16(bf16x8 a, bf16x8 b, f32x4 c) {
  return __builtin_amdgcn_mfma_f32_16x16x32_bf16(a, b, c, 0, 0, 0);
}
__device__ __forceinline__ f32x16 mfma32(bf16x8 a, bf16x8 b, f32x16 c) {
  return __builtin_amdgcn_mfma_f32_32x32x16_bf16(a, b, c, 0, 0, 0);
}

__device__ __forceinline__ void gld_lds16(const void* g, void* l) {
  __builtin_amdgcn_global_load_lds(
      (__attribute__((address_space(1))) void*)(g),
      (__attribute__((address_space(3))) void*)(l), 16, 0, 0);
}

#if __has_builtin(__builtin_amdgcn_exp2f)
#define EXP2F(x) __builtin_amdgcn_exp2f(x)
#else
#define EXP2F(x) __expf(0.69314718056f * (x))
#endif

__device__ __forceinline__ unsigned int cvtpk_bf16(float lo, float hi) {
  unsigned int r;
  asm("v_cvt_pk_bf16_f32 %0, %1, %2" : "=v"(r) : "v"(lo), "v"(hi));
  return r;
}
__device__ __forceinline__ void swap32(unsigned int& x, unsigned int& y) {
  asm("v_permlane32_swap_b32 %0, %1" : "+v"(x), "+v"(y));
}
__device__ __forceinline__ unsigned short bfu(float v) {
  __bf16 h = (__bf16)v;
  return __builtin_bit_cast(unsigned short, h);
}

// ---------- fused: f32->bf16 converts (x, Wq..Wo) + trig table ----------
__global__ void prep_kernel(const float* __restrict__ x, const float* __restrict__ Wq,
                            const float* __restrict__ Wk, const float* __restrict__ Wv,
                            const float* __restrict__ Wo, const int* __restrict__ pos,
                            __bf16* __restrict__ xb, __bf16* __restrict__ Wb,
                            float2* __restrict__ tab) {
  const int bid = blockIdx.x, tid = threadIdx.x;
  if (bid >= 4096) {  // trig table: 256 blocks x 256 threads = 65536 = 2048*32
    int i = (bid - 4096) * 256 + tid;
    int s = i >> 5, j = i & 31;
    float p = (float)pos[s];
    float inv = exp2f((float)j * -0.41524101186098283f);  // -(2/64)*log2(10000)
    float f = p * inv;
    float sn, cs;
    sincosf(f, &sn, &cs);
    tab[i] = make_float2(cs, sn);
    return;
  }
  const float* s;
  __bf16* d;
  size_t base;
  if (bid < 2048) { s = x; d = xb; base = bid; }
  else {
    int seg = (bid - 2048) >> 9;  // 0..3, block-uniform
    s = (seg == 0) ? Wq : (seg == 1) ? Wk : (seg == 2) ? Wv : Wo;
    d = Wb + (size_t)seg * 1024 * 1024;
    base = (bid - 2048) & 511;
  }
  size_t i = (base * 256 + tid) * 8;
  float4 a = *reinterpret_cast<const float4*>(s + i);
  float4 b = *reinterpret_cast<const float4*>(s + i + 4);
  bf16x8 o;
  o[0] = (__bf16)a.x; o[1] = (__bf16)a.y; o[2] = (__bf16)a.z; o[3] = (__bf16)a.w;
  o[4] = (__bf16)b.x; o[5] = (__bf16)b.y; o[6] = (__bf16)b.z; o[7] = (__bf16)b.w;
  *reinterpret_cast<bf16x8*>(d + i) = o;
}

// ---------- C[M][N] = A[M][K] * B[N][K]^T, dbuf LDS + early prefetch ----------
// XCD-banded tile map: XCD x owns M-band [x*MB*128, (x+1)*MB*128) (MB=MT/8;
// A-band 1 MB stays L2-resident) and sweeps all n-panels, m-fastest -> per-XCD
// L2 working set ~3 MB < 4 MB. Requires gridDim.x % 8 == 0 and MT % 8 == 0.
// MODE 0: plain store (OutT). MODE 1 (QKV): cols<2048 -> RoPE into qkv;
// cols>=2048 -> V written TRANSPOSED into Vt[(b*16+h)*64+d][s].
template <typename OutT, int MODE>
__global__ __launch_bounds__(256) void gemm_bt_kernel(
    const __bf16* __restrict__ A, const __bf16* __restrict__ Bw,
    OutT* __restrict__ C, __bf16* __restrict__ Vt,
    int MT, int N, int K, const float2* __restrict__ tab) {
  __shared__ __align__(16) __bf16 lA[2][128 * 32];
  __shared__ __align__(16) __bf16 lB[2][128 * 32];
  const int tid = threadIdx.x;
  const int lane = tid & 63;
  const int wave = tid >> 6;
  const int wr = wave >> 1, wc = wave & 1;

  const int cpx = (int)gridDim.x >> 3;
  const int flat = blockIdx.x;
  const int wg = (flat & 7) * cpx + (flat >> 3);   // XCD x -> wg in [x*cpx,(x+1)*cpx)
  const int MB = MT >> 3;                          // m-tiles per band (4)
  const int NT = (int)gridDim.x / MT;
  const int band = wg / (MB * NT);
  const int inner = wg % (MB * NT);
  const int m0 = (band * MB + (inner % MB)) * 128;  // m-fastest within band
  const int n0 = (inner / MB) * 128;

  const f32x4 fzero = {0.f, 0.f, 0.f, 0.f};
  f32x4 acc[4][4];
#pragma unroll
  for (int i = 0; i < 4; ++i)
#pragma unroll
    for (int j = 0; j < 4; ++j) acc[i][j] = fzero;

  const int srow = tid >> 2, scol = (tid & 3) * 8;
  const __bf16* gA = A + (size_t)(m0 + srow) * K + scol;
  const __bf16* gB = Bw + (size_t)(n0 + srow) * K + scol;
  const size_t half = (size_t)64 * K;
  const int lrow = lane & 15, lk8 = (lane >> 4) * 8;

  // prologue: stage k-tile 0 into buf 0
  gld_lds16(gA, &lA[0][tid * 8]);
  gld_lds16(gA + half, &lA[0][tid * 8 + 2048]);
  gld_lds16(gB, &lB[0][tid * 8]);
  gld_lds16(gB + half, &lB[0][tid * 8 + 2048]);
  __syncthreads();

  const int nk = K >> 5;
  for (int t = 0; t < nk; ++t) {
    const int buf = t & 1;
    if (t + 1 < nk) {  // early prefetch: flies during ds_read + MFMA below
      const int kt = (t + 1) * 32;
      gld_lds16(gA + kt, &lA[buf ^ 1][tid * 8]);
      gld_lds16(gA + kt + half, &lA[buf ^ 1][tid * 8 + 2048]);
      gld_lds16(gB + kt, &lB[buf ^ 1][tid * 8]);
      gld_lds16(gB + kt + half, &lB[buf ^ 1][tid * 8 + 2048]);
    }
    bf16x8 af[4], bfr[4];
#pragma unroll
    for (int i = 0; i < 4; ++i)
      af[i] = *reinterpret_cast<const bf16x8*>(&lA[buf][(wr * 64 + i * 16 + lrow) * 32 + lk8]);
#pragma unroll
    for (int j = 0; j < 4; ++j)
      bfr[j] = *reinterpret_cast<const bf16x8*>(&lB[buf][(wc * 64 + j * 16 + lrow) * 32 + lk8]);
    __builtin_amdgcn_s_setprio(1);
#pragma unroll
    for (int i = 0; i < 4; ++i)
#pragma unroll
      for (int j = 0; j < 4; ++j) acc[i][j] = mfma16(af[i], bfr[j], acc[i][j]);
    __builtin_amdgcn_s_setprio(0);
    __syncthreads();  // drains prefetch (vmcnt 0) + all waves done reading buf
  }

  // C/D layout: col = lane&15, row = (lane>>4)*4 + reg
  const int crow = (lane >> 4) * 4, ccol = lane & 15;
  if (MODE == 1 && n0 < 2048) {  // q,k columns: RoPE epilogue
    const int par = ccol & 1;
#pragma unroll
    for (int i = 0; i < 4; ++i) {
#pragma unroll
      for (int t = 0; t < 4; ++t) {
        const int r = m0 + wr * 64 + i * 16 + crow + t;
        const int s = r & (SS - 1);
#pragma unroll
        for (int j = 0; j < 4; ++j) {
          const int jj = ((j * 16 + ccol) >> 1) & 31;
          float2 cs = tab[(s << 5) | jj];
          float v = acc[i][j][t];
          float o = __shfl_xor(v, 1);
          float y = par ? fmaf(o, cs.y, v * cs.x) : fmaf(v, cs.x, -o * cs.y);
          const int c = n0 + wc * 64 + j * 16 + ccol;
          C[(size_t)r * N + c] = (OutT)y;
        }
      }
    }
  } else if (MODE == 1) {  // V columns: write transposed into Vt
#pragma unroll
    for (int i = 0; i < 4; ++i) {
      const int r0 = m0 + wr * 64 + i * 16 + crow;  // +t stays in same batch
      const int bb = r0 >> 11, s0 = r0 & (SS - 1);
#pragma unroll
      for (int j = 0; j < 4; ++j) {
        const int c = n0 - 2048 + wc * 64 + j * 16 + ccol;
        const int hh = c >> 6, dd = c & 63;
        u16x4 pk;
#pragma unroll
        for (int t = 0; t < 4; ++t) pk[t] = bfu(acc[i][j][t]);
        *reinterpret_cast<u16x4*>(Vt + ((size_t)(bb * 16 + hh) * 64 + dd) * SS + s0) = pk;
      }
    }
  } else {
#pragma unroll
    for (int i = 0; i < 4; ++i) {
#pragma unroll
      for (int j = 0; j < 4; ++j) {
        int r = m0 + wr * 64 + i * 16 + crow;
        int c = n0 + wc * 64 + j * 16 + ccol;
#pragma unroll
        for (int t = 0; t < 4; ++t) C[(size_t)(r + t) * N + c] = (OutT)acc[i][j][t];
      }
    }
  }
}

// ---------- causal flash attention, 32x32 swapped-operand structure ----------
// 2 waves/block (128 thr), 64 q-rows/block (32/wave), KV tile 64, dbuf LDS
// via global_load_lds with source-side XOR swizzle. Grid 1024 = 4 blocks/CU
// (8 waves/CU); bid->qt map makes each CU-group {g=0..3, same c} sum to 66
// rounds: qt in {low, 31-low, 15-low, 16+low}. In-register softmax,
// defer-max (T13), cvt_pk+permlane P conversion (T12), setprio (T5).
#define CEXP 0.18033688011112042f    // log2(e)/8
#define DMAX_THR 11.541560327111708f  // 8 * log2(e)

__global__ __launch_bounds__(128) void attn_kernel(const __bf16* __restrict__ qkv,
                                                   const __bf16* __restrict__ Vt,
                                                   __bf16* __restrict__ AO) {
  const int bid = blockIdx.x;
  const int g = bid >> 8, c = bid & 255;
  const int b = c >> 7, h = (c >> 3) & 15, low = c & 7;
  const int qt = (g == 0) ? low : (g == 1) ? 31 - low : (g == 2) ? 15 - low : 16 + low;

  const int tid = threadIdx.x;
  const int wave = tid >> 6, lane = tid & 63;
  const int q32 = lane & 31, hi = lane >> 5;
  const int qw0 = qt * 64 + wave * 32;
  const int q = qw0 + q32;

  __shared__ __align__(16) __bf16 smem[16384];  // 32 KB: lK[2]|lV[2]; lO aliases
  __bf16* lK0 = smem;
  __bf16* lV0 = smem + 8192;

  // Q fragments (B-operand of QK^T): lane holds Q[q][slot*16 + hi*8 + 0..7]
  bf16x8 qb[4];
  {
    const __bf16* qr = qkv + (size_t)(b * SS + q) * 3072 + h * 64;
#pragma unroll
    for (int slot = 0; slot < 4; ++slot)
      qb[slot] = *reinterpret_cast<const bf16x8*>(qr + slot * 16 + hi * 8);
  }

  const __bf16* kbase = qkv + (size_t)(b * SS) * 3072 + 1024 + h * 64;
  const __bf16* vbase = Vt + (size_t)((b * 16 + h) * 64) * SS;

  // staging: each thread stages rows srow+16u, chunk scg; source col pre-XOR'd
  const int srow = tid >> 3, scg = tid & 7;
  const int ssc = 8 * (scg ^ (srow & 7));
  const __bf16* kG0 = kbase + (size_t)srow * 3072 + ssc;
  const __bf16* vG0 = vbase + (size_t)srow * SS + ssc;

#define STAGE(buf_, kt_)                                                      \
  do {                                                                        \
    const __bf16* kG = kG0 + (size_t)(kt_)*64 * 3072;                         \
    const __bf16* vG = vG0 + (size_t)(kt_)*64;                                \
    _Pragma("unroll") for (int u = 0; u < 4; ++u) {                           \
      gld_lds16(kG + (size_t)u * 16 * 3072, lK0 + (buf_)*4096 + tid * 8 + u * 1024); \
      gld_lds16(vG + (size_t)u * 16 * SS, lV0 + (buf_)*4096 + tid * 8 + u * 1024);   \
    }                                                                         \
  } while (0)

  f32x16 o0 = {0,0,0,0,0,0,0,0,0,0,0,0,0,0,0,0};
  f32x16 o1 = {0,0,0,0,0,0,0,0,0,0,0,0,0,0,0,0};
  float mB = -INFINITY, lsum = 0.f;

  const int nkt = qt + 1;
  STAGE(0, 0);
  __syncthreads();

  for (int kt = 0; kt < nkt; ++kt) {
    const int buf = kt & 1;
    const int kvb = kt * 64;
    if (kt + 1 < nkt) STAGE(buf ^ 1, kt + 1);  // early prefetch

    const __bf16* lk = lK0 + buf * 4096;
    const __bf16* lv = lV0 + buf * 4096;

    // ---- QK^T: S^T[64 kv][32 q] = K-tile * Q^T, contract d=64 ----
    f32x16 s0 = {0,0,0,0,0,0,0,0,0,0,0,0,0,0,0,0};
    f32x16 s1 = {0,0,0,0,0,0,0,0,0,0,0,0,0,0,0,0};
    __builtin_amdgcn_s_setprio(1);
#pragma unroll
    for (int slot = 0; slot < 4; ++slot) {
      const int swz = 8 * ((slot * 2 + hi) ^ (q32 & 7));
      bf16x8 k0 = *reinterpret_cast<const bf16x8*>(lk + q32 * 64 + swz);
      bf16x8 k1 = *reinterpret_cast<const bf16x8*>(lk + (32 + q32) * 64 + swz);
      s0 = mfma32(k0, qb[slot], s0);
      s1 = mfma32(k1, qb[slot], s1);
    }
    __builtin_amdgcn_s_setprio(0);

    // ---- causal mask: only the diagonal tile needs it ----
    if (kt == qt) {
#pragma unroll
      for (int r = 0; r < 16; ++r) {
        const int rowc = (r & 3) + 8 * (r >> 2) + 4 * hi;
        if (kvb + rowc > q) s0[r] = -INFINITY;
        if (kvb + 32 + rowc > q) s1[r] = -INFINITY;
      }
    }

    // ---- online softmax, lane-local row, defer-max ----
    float pm = s0[0];
#pragma unroll
    for (int r = 1; r < 16; ++r) pm = fmaxf(pm, s0[r]);
#pragma unroll
    for (int r = 0; r < 16; ++r) pm = fmaxf(pm, s1[r]);
    pm = fmaxf(pm, __shfl_xor(pm, 32));
    const float pmB = pm * CEXP;
    if (!__all(pmB <= mB + DMAX_THR)) {
      const float mnB = fmaxf(mB, pmB);
      const float alpha = EXP2F(mB - mnB);
      mB = mnB;
      lsum *= alpha;
#pragma unroll
      for (int r = 0; r < 16; ++r) { o0[r] *= alpha; o1[r] *= alpha; }
    }
    float rs = 0.f;
#pragma unroll
    for (int r = 0; r < 16; ++r) { s0[r] = EXP2F(fmaf(s0[r], CEXP, -mB)); rs += s0[r]; }
#pragma unroll
    for (int r = 0; r < 16; ++r) { s1[r] = EXP2F(fmaf(s1[r], CEXP, -mB)); rs += s1[r]; }
    rs += __shfl_xor(rs, 32);
    lsum += rs;

    // ---- P -> bf16 PV fragments (cvt_pk + permlane32_swap) ----
    bf16x8 pb[4];
    {
      unsigned int A = cvtpk_bf16(s0[0], s0[1]), B2 = cvtpk_bf16(s0[2], s0[3]);
      unsigned int C2 = cvtpk_bf16(s0[4], s0[5]), D2 = cvtpk_bf16(s0[6], s0[7]);
      swap32(A, C2); swap32(B2, D2);
      u32x4 t0 = {A, B2, C2, D2};
      pb[0] = __builtin_bit_cast(bf16x8, t0);
      unsigned int E = cvtpk_bf16(s0[8], s0[9]), F = cvtpk_bf16(s0[10], s0[11]);
      unsigned int G = cvtpk_bf16(s0[12], s0[13]), H = cvtpk_bf16(s0[14], s0[15]);
      swap32(E, G); swap32(F, H);
      u32x4 t1 = {E, F, G, H};
      pb[1] = __builtin_bit_cast(bf16x8, t1);
      unsigned int A3 = cvtpk_bf16(s1[0], s1[1]), B3 = cvtpk_bf16(s1[2], s1[3]);
      unsigned int C3 = cvtpk_bf16(s1[4], s1[5]), D3 = cvtpk_bf16(s1[6], s1[7]);
      swap32(A3, C3); swap32(B3, D3);
      u32x4 t2 = {A3, B3, C3, D3};
      pb[2] = __builtin_bit_cast(bf16x8, t2);
      unsigned int E3 = cvtpk_bf16(s1[8], s1[9]), F3 = cvtpk_bf16(s1[10], s1[11]);
      unsigned int G3 = cvtpk_bf16(s1[12], s1[13]), H3 = cvtpk_bf16(s1[14], s1[15]);
      swap32(E3, G3); swap32(F3, H3);
      u32x4 t3 = {E3, F3, G3, H3};
      pb[3] = __builtin_bit_cast(bf16x8, t3);
    }

    // ---- PV: O^T[64 d][32 q] += V^T-slot * P^T-slot ----
    __builtin_amdgcn_s_setprio(1);
#pragma unroll
    for (int slot = 0; slot < 4; ++slot) {
      const int swz = 8 * ((slot * 2 + hi) ^ (q32 & 7));
      bf16x8 v0 = *reinterpret_cast<const bf16x8*>(lv + q32 * 64 + swz);
      bf16x8 v1 = *reinterpret_cast<const bf16x8*>(lv + (32 + q32) * 64 + swz);
      o0 = mfma32(v0, pb[slot], o0);
      o1 = mfma32(v1, pb[slot], o1);
    }
    __builtin_amdgcn_s_setprio(0);

    __syncthreads();  // staged loads drained + all waves done with buf
  }

  // ---- epilogue: O^T/lsum -> per-wave LDS transpose -> coalesced stores ----
  const float inv = 1.0f / lsum;
  __bf16* ol = smem + wave * 2304;  // aliases lK (safe: after final barrier)
#pragma unroll
  for (int r = 0; r < 16; ++r) {
    const int d = (r & 3) + 8 * (r >> 2) + 4 * hi;
    ol[q32 * 72 + d] = (__bf16)(o0[r] * inv);
    ol[q32 * 72 + 32 + d] = (__bf16)(o1[r] * inv);
  }
  // per-wave buffer: in-wave lgkm ordering suffices, no barrier needed
#pragma unroll
  for (int pass = 0; pass < 4; ++pass) {
    const int idx = pass * 64 + lane;
    const int row = idx >> 3, colc = idx & 7;
    bf16x8 v = *reinterpret_cast<const bf16x8*>(ol + row * 72 + colc * 8);
    *reinterpret_cast<bf16x8*>(
        AO + (size_t)(b * SS + qt * 64 + wave * 32 + row) * 1024 + h * 64 + colc * 8) = v;
  }
#undef STAGE
}

extern "C" void kernel_launch(void* const* d_in, const int* in_sizes, int n_in,
                              void* d_out, int out_size, void* d_ws, size_t ws_size,
                              hipStream_t stream) {
  const float* x  = (const float*)d_in[0];
  const int* pos  = (const int*)d_in[1];
  const float* Wq = (const float*)d_in[2];
  const float* Wk = (const float*)d_in[3];
  const float* Wv = (const float*)d_in[4];
  const float* Wo = (const float*)d_in[5];

  __bf16* xb  = (__bf16*)d_ws;                        // [4096][1024]
  __bf16* Wb  = xb + (size_t)4096 * 1024;             // [4096][1024] = Wq;Wk;Wv;Wo stacked
  __bf16* qkv = Wb + (size_t)4096 * 1024;             // [4096][3072] (q|k cols live; v unused)
  __bf16* Vt  = qkv + (size_t)4096 * 3072;            // [2*16*64][2048]
  __bf16* ao  = Vt + (size_t)2048 * 2048;             // [4096][1024]
  float2* tab = (float2*)(ao + (size_t)4096 * 1024);  // [2048*32]

  prep_kernel<<<4352, 256, 0, stream>>>(x, Wq, Wk, Wv, Wo, pos, xb, Wb, tab);

  // fused QKV projection + RoPE + V-transpose epilogue
  gemm_bt_kernel<__bf16, 1><<<768, 256, 0, stream>>>(
      xb, Wb, qkv, Vt, 32, 3072, 1024, tab);
  attn_kernel<<<1024, 128, 0, stream>>>(qkv, Vt, ao);
  gemm_bt_kernel<float, 0><<<256, 256, 0, stream>>>(
      ao, Wb + (size_t)3 * 1024 * 1024, (float*)d_out, nullptr, 32, 1024, 1024, nullptr);
}

// Round 7
// 117.500 us; speedup vs baseline: 1.3916x; 1.0900x over previous
//
#include <hip/hip_runtime.h>
#include <hip/hip_bf16.h>
#include <math.h>

// Problem constants (from reference): B=2, S=2048, D_MODEL=1024, H=16, D_K=64
#define SS 2048

typedef __attribute__((ext_vector_type(8))) __bf16 bf16x8;
typedef __attribute__((ext_vector_type(4))) float f32x4;
typedef __attribute__((ext_vector_type(16))) float f32x16;
typedef __attribute__((ext_vector_type(4))) unsigned int u32x4;
typedef __attribute__((ext_vector_type(4))) unsigned short u16x4;

__device__ __forceinline__ f32x4 mfma16(bf16x8 a, bf16x8 b, f32x4 c) {
  return __builtin_amdgcn_mfma_f32_16x16x32_bf16(a, b, c, 0, 0, 0);
}
__device__ __forceinline__ f32x16 mfma32(bf16x8 a, bf16x8 b, f32x16 c) {
  return __builtin_amdgcn_mfma_f32_32x32x16_bf16(a, b, c, 0, 0, 0);
}

__device__ __forceinline__ void gld_lds16(const void* g, void* l) {
  __builtin_amdgcn_global_load_lds(
      (__attribute__((address_space(1))) void*)(g),
      (__attribute__((address_space(3))) void*)(l), 16, 0, 0);
}

#if __has_builtin(__builtin_amdgcn_exp2f)
#define EXP2F(x) __builtin_amdgcn_exp2f(x)
#else
#define EXP2F(x) __expf(0.69314718056f * (x))
#endif

__device__ __forceinline__ unsigned int cvtpk_bf16(float lo, float hi) {
  unsigned int r;
  asm("v_cvt_pk_bf16_f32 %0, %1, %2" : "=v"(r) : "v"(lo), "v"(hi));
  return r;
}
__device__ __forceinline__ void swap32(unsigned int& x, unsigned int& y) {
  asm("v_permlane32_swap_b32 %0, %1" : "+v"(x), "+v"(y));
}
__device__ __forceinline__ unsigned short bfu(float v) {
  __bf16 h = (__bf16)v;
  return __builtin_bit_cast(unsigned short, h);
}

// ---------- fused: f32->bf16 converts (x, Wq..Wo) + trig table ----------
__global__ void prep_kernel(const float* __restrict__ x, const float* __restrict__ Wq,
                            const float* __restrict__ Wk, const float* __restrict__ Wv,
                            const float* __restrict__ Wo, const int* __restrict__ pos,
                            __bf16* __restrict__ xb, __bf16* __restrict__ Wb,
                            float2* __restrict__ tab) {
  const int bid = blockIdx.x, tid = threadIdx.x;
  if (bid >= 4096) {  // trig table: 256 blocks x 256 threads = 65536 = 2048*32
    int i = (bid - 4096) * 256 + tid;
    int s = i >> 5, j = i & 31;
    float p = (float)pos[s];
    float inv = exp2f((float)j * -0.41524101186098283f);  // -(2/64)*log2(10000)
    float f = p * inv;
    float sn, cs;
    sincosf(f, &sn, &cs);
    tab[i] = make_float2(cs, sn);
    return;
  }
  const float* s;
  __bf16* d;
  size_t base;
  if (bid < 2048) { s = x; d = xb; base = bid; }
  else {
    int seg = (bid - 2048) >> 9;  // 0..3, block-uniform
    s = (seg == 0) ? Wq : (seg == 1) ? Wk : (seg == 2) ? Wv : Wo;
    d = Wb + (size_t)seg * 1024 * 1024;
    base = (bid - 2048) & 511;
  }
  size_t i = (base * 256 + tid) * 8;
  float4 a = *reinterpret_cast<const float4*>(s + i);
  float4 b = *reinterpret_cast<const float4*>(s + i + 4);
  bf16x8 o;
  o[0] = (__bf16)a.x; o[1] = (__bf16)a.y; o[2] = (__bf16)a.z; o[3] = (__bf16)a.w;
  o[4] = (__bf16)b.x; o[5] = (__bf16)b.y; o[6] = (__bf16)b.z; o[7] = (__bf16)b.w;
  *reinterpret_cast<bf16x8*>(d + i) = o;
}

// ---------- 256x256 QKV GEMM: counted-vmcnt pipeline (T3/T4) ----------
// C[M][N] = A[M][K]*Bw[N][K]^T, BK=32, 8 waves (2M x 4N), 4-slot LDS
// rotation (slot = kt&3, 128 KiB), global_load_lds staging with chunk-XOR
// swizzle (source-side), ONE raw s_barrier per K-tile preceded by
// s_waitcnt vmcnt(8) (2 K-tiles in flight; never drained to 0 mid-loop).
// Epilogue: cols<2048 -> RoPE into qkv; cols>=2048 -> V transposed to Vt.
__global__ __launch_bounds__(512, 1) void gemm256_kernel(
    const __bf16* __restrict__ A, const __bf16* __restrict__ Bw,
    __bf16* __restrict__ C, __bf16* __restrict__ Vt,
    const float2* __restrict__ tab) {
  const int K = 1024, N = 3072, nk = 32;  // K/32 tiles
  __shared__ __align__(16) __bf16 sm[65536];  // 128 KiB: A slots | B slots
  __bf16* lsA = sm;
  __bf16* lsB = sm + 32768;

  const int tid = threadIdx.x;
  const int lane = tid & 63;
  const int wave = tid >> 6;
  const int wr = wave >> 2, wc = wave & 3;  // 2M x 4N wave grid

  // XCD-banded tile map: grid 192 = 16 m-tiles x 12 n-tiles, 24 blocks/XCD,
  // each XCD owns 2 m-tiles (1 MB A band), m-fastest.
  const int xcd = blockIdx.x & 7;
  const int ii = blockIdx.x >> 3;  // 0..23
  const int m0 = (2 * xcd + (ii & 1)) * 256;
  const int n0 = (ii >> 1) * 256;

  const f32x4 fzero = {0.f, 0.f, 0.f, 0.f};
  f32x4 acc[8][4];
#pragma unroll
  for (int f = 0; f < 8; ++f)
#pragma unroll
    for (int g = 0; g < 4; ++g) acc[f][g] = fzero;

  // staging geometry: thread -> (row = tid>>2 in [0,128), chunk = tid&3);
  // source chunk pre-XOR'd so LDS[row][chunk] = global chunk^((row>>1)&3)
  const int srow = tid >> 2, schunk = tid & 3;
  const int ssc = schunk ^ ((srow >> 1) & 3);
  const __bf16* gA = A + (size_t)(m0 + srow) * K + ssc * 8;
  const __bf16* gB = Bw + (size_t)(n0 + srow) * K + ssc * 8;
  const size_t half128 = (size_t)128 * K;

#define STAGE256(kt_)                                              \
  do {                                                             \
    const int kc_ = (kt_) & 3;                                     \
    const __bf16* ga_ = gA + (size_t)(kt_) * 32;                   \
    const __bf16* gb_ = gB + (size_t)(kt_) * 32;                   \
    gld_lds16(ga_, lsA + kc_ * 8192 + tid * 8);                    \
    gld_lds16(ga_ + half128, lsA + kc_ * 8192 + 4096 + tid * 8);   \
    gld_lds16(gb_, lsB + kc_ * 8192 + tid * 8);                    \
    gld_lds16(gb_ + half128, lsB + kc_ * 8192 + 4096 + tid * 8);   \
  } while (0)

  // prologue: 2 K-tiles in flight
  STAGE256(0);
  STAGE256(1);

  const int lrow = lane & 15, hi = lane >> 4;

#pragma unroll 1
  for (int kt = 0; kt < nk; ++kt) {
    const int ks = (kt & 3) * 8192;
    if (kt + 2 < nk) {
      STAGE256(kt + 2);
      asm volatile("s_waitcnt vmcnt(8)" ::: "memory");  // slot kt landed (mine)
    } else if (kt == nk - 2) {
      asm volatile("s_waitcnt vmcnt(4)" ::: "memory");
    } else {
      asm volatile("s_waitcnt vmcnt(0)" ::: "memory");
    }
    __builtin_amdgcn_s_barrier();  // everyone's slot-kt loads landed

    // B fragments (held across both phases)
    bf16x8 bfr[4];
#pragma unroll
    for (int g = 0; g < 4; ++g) {
      const int r = wc * 64 + g * 16 + lrow;
      bfr[g] = *reinterpret_cast<const bf16x8*>(
          lsB + ks + r * 32 + ((hi ^ ((r >> 1) & 3)) * 8));
    }
    // phase 0: m-frags 0..3
    bf16x8 af[4];
#pragma unroll
    for (int f = 0; f < 4; ++f) {
      const int r = wr * 128 + f * 16 + lrow;
      af[f] = *reinterpret_cast<const bf16x8*>(
          lsA + ks + r * 32 + ((hi ^ ((r >> 1) & 3)) * 8));
    }
    __builtin_amdgcn_s_setprio(1);
#pragma unroll
    for (int f = 0; f < 4; ++f)
#pragma unroll
      for (int g = 0; g < 4; ++g) acc[f][g] = mfma16(af[f], bfr[g], acc[f][g]);
    __builtin_amdgcn_s_setprio(0);
    // phase 1: m-frags 4..7
#pragma unroll
    for (int f = 0; f < 4; ++f) {
      const int r = wr * 128 + (f + 4) * 16 + lrow;
      af[f] = *reinterpret_cast<const bf16x8*>(
          lsA + ks + r * 32 + ((hi ^ ((r >> 1) & 3)) * 8));
    }
    __builtin_amdgcn_s_setprio(1);
#pragma unroll
    for (int f = 0; f < 4; ++f)
#pragma unroll
      for (int g = 0; g < 4; ++g) acc[f + 4][g] = mfma16(af[f], bfr[g], acc[f + 4][g]);
    __builtin_amdgcn_s_setprio(0);
    // no trailing barrier: next iter's barrier bounds skew; 4-slot rotation
    // guarantees stage targets are >=2 slots away from any readable slot.
  }
#undef STAGE256

  // ---- epilogue (C/D layout: col = lane&15, row = (lane>>4)*4 + t) ----
  const int crow = (lane >> 4) * 4, ccol = lane & 15;
  if (n0 < 2048) {  // q,k columns: RoPE
    const int par = ccol & 1;
#pragma unroll
    for (int f = 0; f < 8; ++f) {
#pragma unroll
      for (int t = 0; t < 4; ++t) {
        const int r = m0 + wr * 128 + f * 16 + crow + t;
        const int s = r & (SS - 1);
#pragma unroll
        for (int g = 0; g < 4; ++g) {
          const int c = n0 + wc * 64 + g * 16 + ccol;
          const int jj = (c >> 1) & 31;
          float2 cs = tab[(s << 5) | jj];
          float v = acc[f][g][t];
          float o = __shfl_xor(v, 1);
          float y = par ? fmaf(o, cs.y, v * cs.x) : fmaf(v, cs.x, -o * cs.y);
          C[(size_t)r * N + c] = (__bf16)y;
        }
      }
    }
  } else {  // V columns: write transposed into Vt[(b*16+h)*64+d][s]
#pragma unroll
    for (int f = 0; f < 8; ++f) {
      const int r0 = m0 + wr * 128 + f * 16 + crow;
      const int bb = r0 >> 11, s0 = r0 & (SS - 1);
#pragma unroll
      for (int g = 0; g < 4; ++g) {
        const int c = n0 - 2048 + wc * 64 + g * 16 + ccol;
        const int hh = c >> 6, dd = c & 63;
        u16x4 pk;
#pragma unroll
        for (int t = 0; t < 4; ++t) pk[t] = bfu(acc[f][g][t]);
        *reinterpret_cast<u16x4*>(Vt + ((size_t)(bb * 16 + hh) * 64 + dd) * SS + s0) = pk;
      }
    }
  }
}

// ---------- 128x128 GEMM (m97 structure) for the output projection ----------
template <typename OutT>
__global__ __launch_bounds__(256) void gemm_bt_kernel(
    const __bf16* __restrict__ A, const __bf16* __restrict__ Bw,
    OutT* __restrict__ C, int MT, int N, int K) {
  __shared__ __align__(16) __bf16 lA[2][128 * 32];
  __shared__ __align__(16) __bf16 lB[2][128 * 32];
  const int tid = threadIdx.x;
  const int lane = tid & 63;
  const int wave = tid >> 6;
  const int wr = wave >> 1, wc = wave & 1;

  const int cpx = (int)gridDim.x >> 3;
  const int flat = blockIdx.x;
  const int wg = (flat & 7) * cpx + (flat >> 3);
  const int MB = MT >> 3;
  const int NT = (int)gridDim.x / MT;
  const int band = wg / (MB * NT);
  const int inner = wg % (MB * NT);
  const int m0 = (band * MB + (inner % MB)) * 128;
  const int n0 = (inner / MB) * 128;

  const f32x4 fzero = {0.f, 0.f, 0.f, 0.f};
  f32x4 acc[4][4];
#pragma unroll
  for (int i = 0; i < 4; ++i)
#pragma unroll
    for (int j = 0; j < 4; ++j) acc[i][j] = fzero;

  const int srow = tid >> 2, scol = (tid & 3) * 8;
  const __bf16* gA = A + (size_t)(m0 + srow) * K + scol;
  const __bf16* gB = Bw + (size_t)(n0 + srow) * K + scol;
  const size_t half = (size_t)64 * K;
  const int lrow = lane & 15, lk8 = (lane >> 4) * 8;

  gld_lds16(gA, &lA[0][tid * 8]);
  gld_lds16(gA + half, &lA[0][tid * 8 + 2048]);
  gld_lds16(gB, &lB[0][tid * 8]);
  gld_lds16(gB + half, &lB[0][tid * 8 + 2048]);
  __syncthreads();

  const int nk = K >> 5;
  for (int t = 0; t < nk; ++t) {
    const int buf = t & 1;
    if (t + 1 < nk) {
      const int kt = (t + 1) * 32;
      gld_lds16(gA + kt, &lA[buf ^ 1][tid * 8]);
      gld_lds16(gA + kt + half, &lA[buf ^ 1][tid * 8 + 2048]);
      gld_lds16(gB + kt, &lB[buf ^ 1][tid * 8]);
      gld_lds16(gB + kt + half, &lB[buf ^ 1][tid * 8 + 2048]);
    }
    bf16x8 af[4], bfr[4];
#pragma unroll
    for (int i = 0; i < 4; ++i)
      af[i] = *reinterpret_cast<const bf16x8*>(&lA[buf][(wr * 64 + i * 16 + lrow) * 32 + lk8]);
#pragma unroll
    for (int j = 0; j < 4; ++j)
      bfr[j] = *reinterpret_cast<const bf16x8*>(&lB[buf][(wc * 64 + j * 16 + lrow) * 32 + lk8]);
    __builtin_amdgcn_s_setprio(1);
#pragma unroll
    for (int i = 0; i < 4; ++i)
#pragma unroll
      for (int j = 0; j < 4; ++j) acc[i][j] = mfma16(af[i], bfr[j], acc[i][j]);
    __builtin_amdgcn_s_setprio(0);
    __syncthreads();
  }

  const int crow = (lane >> 4) * 4, ccol = lane & 15;
#pragma unroll
  for (int i = 0; i < 4; ++i) {
#pragma unroll
    for (int j = 0; j < 4; ++j) {
      int r = m0 + wr * 64 + i * 16 + crow;
      int c = n0 + wc * 64 + j * 16 + ccol;
#pragma unroll
      for (int t = 0; t < 4; ++t) C[(size_t)(r + t) * N + c] = (OutT)acc[i][j][t];
    }
  }
}

// ---------- causal flash attention, 32x32 swapped-operand structure ----------
#define CEXP 0.18033688011112042f    // log2(e)/8
#define DMAX_THR 11.541560327111708f  // 8 * log2(e)

__global__ __launch_bounds__(128) void attn_kernel(const __bf16* __restrict__ qkv,
                                                   const __bf16* __restrict__ Vt,
                                                   __bf16* __restrict__ AO) {
  const int bid = blockIdx.x;
  const int g = bid >> 8, c = bid & 255;
  const int b = c >> 7, h = (c >> 3) & 15, low = c & 7;
  const int qt = (g == 0) ? low : (g == 1) ? 31 - low : (g == 2) ? 15 - low : 16 + low;

  const int tid = threadIdx.x;
  const int wave = tid >> 6, lane = tid & 63;
  const int q32 = lane & 31, hi = lane >> 5;
  const int qw0 = qt * 64 + wave * 32;
  const int q = qw0 + q32;

  __shared__ __align__(16) __bf16 smem[16384];  // 32 KB: lK[2]|lV[2]; lO aliases
  __bf16* lK0 = smem;
  __bf16* lV0 = smem + 8192;

  bf16x8 qb[4];
  {
    const __bf16* qr = qkv + (size_t)(b * SS + q) * 3072 + h * 64;
#pragma unroll
    for (int slot = 0; slot < 4; ++slot)
      qb[slot] = *reinterpret_cast<const bf16x8*>(qr + slot * 16 + hi * 8);
  }

  const __bf16* kbase = qkv + (size_t)(b * SS) * 3072 + 1024 + h * 64;
  const __bf16* vbase = Vt + (size_t)((b * 16 + h) * 64) * SS;

  const int srow = tid >> 3, scg = tid & 7;
  const int ssc = 8 * (scg ^ (srow & 7));
  const __bf16* kG0 = kbase + (size_t)srow * 3072 + ssc;
  const __bf16* vG0 = vbase + (size_t)srow * SS + ssc;

#define STAGE(buf_, kt_)                                                      \
  do {                                                                        \
    const __bf16* kG = kG0 + (size_t)(kt_)*64 * 3072;                         \
    const __bf16* vG = vG0 + (size_t)(kt_)*64;                                \
    _Pragma("unroll") for (int u = 0; u < 4; ++u) {                           \
      gld_lds16(kG + (size_t)u * 16 * 3072, lK0 + (buf_)*4096 + tid * 8 + u * 1024); \
      gld_lds16(vG + (size_t)u * 16 * SS, lV0 + (buf_)*4096 + tid * 8 + u * 1024);   \
    }                                                                         \
  } while (0)

  f32x16 o0 = {0,0,0,0,0,0,0,0,0,0,0,0,0,0,0,0};
  f32x16 o1 = {0,0,0,0,0,0,0,0,0,0,0,0,0,0,0,0};
  float mB = -INFINITY, lsum = 0.f;

  const int nkt = qt + 1;
  STAGE(0, 0);
  __syncthreads();

  for (int kt = 0; kt < nkt; ++kt) {
    const int buf = kt & 1;
    const int kvb = kt * 64;
    if (kt + 1 < nkt) STAGE(buf ^ 1, kt + 1);

    const __bf16* lk = lK0 + buf * 4096;
    const __bf16* lv = lV0 + buf * 4096;

    f32x16 s0 = {0,0,0,0,0,0,0,0,0,0,0,0,0,0,0,0};
    f32x16 s1 = {0,0,0,0,0,0,0,0,0,0,0,0,0,0,0,0};
    __builtin_amdgcn_s_setprio(1);
#pragma unroll
    for (int slot = 0; slot < 4; ++slot) {
      const int swz = 8 * ((slot * 2 + hi) ^ (q32 & 7));
      bf16x8 k0 = *reinterpret_cast<const bf16x8*>(lk + q32 * 64 + swz);
      bf16x8 k1 = *reinterpret_cast<const bf16x8*>(lk + (32 + q32) * 64 + swz);
      s0 = mfma32(k0, qb[slot], s0);
      s1 = mfma32(k1, qb[slot], s1);
    }
    __builtin_amdgcn_s_setprio(0);

    if (kt == qt) {
#pragma unroll
      for (int r = 0; r < 16; ++r) {
        const int rowc = (r & 3) + 8 * (r >> 2) + 4 * hi;
        if (kvb + rowc > q) s0[r] = -INFINITY;
        if (kvb + 32 + rowc > q) s1[r] = -INFINITY;
      }
    }

    float pm = s0[0];
#pragma unroll
    for (int r = 1; r < 16; ++r) pm = fmaxf(pm, s0[r]);
#pragma unroll
    for (int r = 0; r < 16; ++r) pm = fmaxf(pm, s1[r]);
    pm = fmaxf(pm, __shfl_xor(pm, 32));
    const float pmB = pm * CEXP;
    if (!__all(pmB <= mB + DMAX_THR)) {
      const float mnB = fmaxf(mB, pmB);
      const float alpha = EXP2F(mB - mnB);
      mB = mnB;
      lsum *= alpha;
#pragma unroll
      for (int r = 0; r < 16; ++r) { o0[r] *= alpha; o1[r] *= alpha; }
    }
    float rs = 0.f;
#pragma unroll
    for (int r = 0; r < 16; ++r) { s0[r] = EXP2F(fmaf(s0[r], CEXP, -mB)); rs += s0[r]; }
#pragma unroll
    for (int r = 0; r < 16; ++r) { s1[r] = EXP2F(fmaf(s1[r], CEXP, -mB)); rs += s1[r]; }
    rs += __shfl_xor(rs, 32);
    lsum += rs;

    bf16x8 pb[4];
    {
      unsigned int A = cvtpk_bf16(s0[0], s0[1]), B2 = cvtpk_bf16(s0[2], s0[3]);
      unsigned int C2 = cvtpk_bf16(s0[4], s0[5]), D2 = cvtpk_bf16(s0[6], s0[7]);
      swap32(A, C2); swap32(B2, D2);
      u32x4 t0 = {A, B2, C2, D2};
      pb[0] = __builtin_bit_cast(bf16x8, t0);
      unsigned int E = cvtpk_bf16(s0[8], s0[9]), F = cvtpk_bf16(s0[10], s0[11]);
      unsigned int G = cvtpk_bf16(s0[12], s0[13]), H = cvtpk_bf16(s0[14], s0[15]);
      swap32(E, G); swap32(F, H);
      u32x4 t1 = {E, F, G, H};
      pb[1] = __builtin_bit_cast(bf16x8, t1);
      unsigned int A3 = cvtpk_bf16(s1[0], s1[1]), B3 = cvtpk_bf16(s1[2], s1[3]);
      unsigned int C3 = cvtpk_bf16(s1[4], s1[5]), D3 = cvtpk_bf16(s1[6], s1[7]);
      swap32(A3, C3); swap32(B3, D3);
      u32x4 t2 = {A3, B3, C3, D3};
      pb[2] = __builtin_bit_cast(bf16x8, t2);
      unsigned int E3 = cvtpk_bf16(s1[8], s1[9]), F3 = cvtpk_bf16(s1[10], s1[11]);
      unsigned int G3 = cvtpk_bf16(s1[12], s1[13]), H3 = cvtpk_bf16(s1[14], s1[15]);
      swap32(E3, G3); swap32(F3, H3);
      u32x4 t3 = {E3, F3, G3, H3};
      pb[3] = __builtin_bit_cast(bf16x8, t3);
    }

    __builtin_amdgcn_s_setprio(1);
#pragma unroll
    for (int slot = 0; slot < 4; ++slot) {
      const int swz = 8 * ((slot * 2 + hi) ^ (q32 & 7));
      bf16x8 v0 = *reinterpret_cast<const bf16x8*>(lv + q32 * 64 + swz);
      bf16x8 v1 = *reinterpret_cast<const bf16x8*>(lv + (32 + q32) * 64 + swz);
      o0 = mfma32(v0, pb[slot], o0);
      o1 = mfma32(v1, pb[slot], o1);
    }
    __builtin_amdgcn_s_setprio(0);

    __syncthreads();
  }

  const float inv = 1.0f / lsum;
  __bf16* ol = smem + wave * 2304;
#pragma unroll
  for (int r = 0; r < 16; ++r) {
    const int d = (r & 3) + 8 * (r >> 2) + 4 * hi;
    ol[q32 * 72 + d] = (__bf16)(o0[r] * inv);
    ol[q32 * 72 + 32 + d] = (__bf16)(o1[r] * inv);
  }
#pragma unroll
  for (int pass = 0; pass < 4; ++pass) {
    const int idx = pass * 64 + lane;
    const int row = idx >> 3, colc = idx & 7;
    bf16x8 v = *reinterpret_cast<const bf16x8*>(ol + row * 72 + colc * 8);
    *reinterpret_cast<bf16x8*>(
        AO + (size_t)(b * SS + qt * 64 + wave * 32 + row) * 1024 + h * 64 + colc * 8) = v;
  }
#undef STAGE
}

extern "C" void kernel_launch(void* const* d_in, const int* in_sizes, int n_in,
                              void* d_out, int out_size, void* d_ws, size_t ws_size,
                              hipStream_t stream) {
  const float* x  = (const float*)d_in[0];
  const int* pos  = (const int*)d_in[1];
  const float* Wq = (const float*)d_in[2];
  const float* Wk = (const float*)d_in[3];
  const float* Wv = (const float*)d_in[4];
  const float* Wo = (const float*)d_in[5];

  __bf16* xb  = (__bf16*)d_ws;                        // [4096][1024]
  __bf16* Wb  = xb + (size_t)4096 * 1024;             // [4096][1024] = Wq;Wk;Wv;Wo stacked
  __bf16* qkv = Wb + (size_t)4096 * 1024;             // [4096][3072] (q|k cols live)
  __bf16* Vt  = qkv + (size_t)4096 * 3072;            // [2*16*64][2048]
  __bf16* ao  = Vt + (size_t)2048 * 2048;             // [4096][1024]
  float2* tab = (float2*)(ao + (size_t)4096 * 1024);  // [2048*32]

  prep_kernel<<<4352, 256, 0, stream>>>(x, Wq, Wk, Wv, Wo, pos, xb, Wb, tab);

  // fused QKV projection + RoPE + V-transpose, 256^2 counted-vmcnt pipeline
  gemm256_kernel<<<192, 512, 0, stream>>>(xb, Wb, qkv, Vt, tab);
  attn_kernel<<<1024, 128, 0, stream>>>(qkv, Vt, ao);
  gemm_bt_kernel<float><<<256, 256, 0, stream>>>(
      ao, Wb + (size_t)3 * 1024 * 1024, (float*)d_out, 32, 1024, 1024);
}